// Round 5
// baseline (445.803 us; speedup 1.0000x reference)
//
#include <hip/hip_runtime.h>
#include <hip/hip_cooperative_groups.h>

// B=2048, D=16384 fp32.
// Fused cooperative kernel, 512 blocks x 256 threads (2 blocks/CU -> co-resident).
// Phase A: 32 row-chunks x 16 col-blocks partial col sums/sumsq   (== round-1 k1)
// Phase B: blocks 0..63 finalize nm/nv + block-partial var sums    (== round-1 k2)
// Phase B2: blocks 0..63 scalar reduce -> inv_denom                (== round-1 k2c)
// Phase C: 4 rows/block argmax + copy-with-substitution            (== round-1 k3)
// Arithmetic order is IDENTICAL to round 1 (absmax 0.0) to keep argmax stable.

namespace {

constexpr int B = 2048;
constexpr int D = 16384;
constexpr int NCHUNK = 32;
constexpr int ROWS_PER_CHUNK = B / NCHUNK;  // 64
constexpr int COLBLKS = D / 1024;           // 16
constexpr int GRID = NCHUNK * COLBLKS;      // 512
constexpr int ROWS_PER_BLOCK = B / GRID;    // 4

__device__ __forceinline__ void phaseA(const float* __restrict__ h,
                                       float* __restrict__ ps,
                                       float* __restrict__ pq,
                                       int bid, int tid) {
    const int colblk = bid & (COLBLKS - 1);
    const int chunk  = bid >> 4;
    const int c0 = colblk * 1024 + tid * 4;
    const float* base = h + (size_t)(chunk * ROWS_PER_CHUNK) * D + c0;
    float4 s = make_float4(0.f, 0.f, 0.f, 0.f);
    float4 q = make_float4(0.f, 0.f, 0.f, 0.f);
#pragma unroll 8
    for (int r = 0; r < ROWS_PER_CHUNK; ++r) {
        float4 v = *reinterpret_cast<const float4*>(base + (size_t)r * D);
        s.x += v.x; s.y += v.y; s.z += v.z; s.w += v.w;
        q.x = fmaf(v.x, v.x, q.x);
        q.y = fmaf(v.y, v.y, q.y);
        q.z = fmaf(v.z, v.z, q.z);
        q.w = fmaf(v.w, v.w, q.w);
    }
    *reinterpret_cast<float4*>(ps + chunk * D + c0) = s;
    *reinterpret_cast<float4*>(pq + chunk * D + c0) = q;
}

__global__ __launch_bounds__(256) void kfused(const float* __restrict__ h,
                                              const float* __restrict__ h_mean,
                                              const float* __restrict__ h_var,
                                              float* __restrict__ out,
                                              float* __restrict__ ps,
                                              float* __restrict__ pq,
                                              float* __restrict__ nm,
                                              float* __restrict__ nv,
                                              float* __restrict__ inv,
                                              float* __restrict__ bsum) {
    cooperative_groups::grid_group grid = cooperative_groups::this_grid();
    const int tid = threadIdx.x;
    const int bid = blockIdx.x;

    __shared__ float red[256];
    __shared__ float ss[256];
    __shared__ int   si[256];

    // ---- Phase A -----------------------------------------------------------
    phaseA(h, ps, pq, bid, tid);
    grid.sync();

    // ---- Phase B (blocks 0..63): finalize column stats --------------------
    if (bid < 64) {
        const int d = bid * 256 + tid;
        float s = 0.f, q = 0.f;
#pragma unroll
        for (int c = 0; c < NCHUNK; ++c) {
            s += ps[c * D + d];
            q += pq[c * D + d];
        }
        constexpr float invB = 1.0f / (float)B;
        const float hu = s * invB;
        const float hv = q * invB - hu * hu;
        const float hm  = h_mean[d];
        const float hvr = h_var[d];
        const float du  = hu - hm;
        const float newvar  = (hvr * (10.0f - invB) + hv + (du * du) / 1.1f) / (11.0f - invB);
        const float newmean = (hm * 10.0f + hu) / 11.0f;
        nm[d] = newmean;
        nv[d] = newvar;

        red[tid] = newvar;
        __syncthreads();
#pragma unroll
        for (int off = 128; off > 0; off >>= 1) {
            if (tid < off) red[tid] += red[tid + off];
            __syncthreads();
        }
        if (tid == 0) bsum[bid] = red[0];
    }
    grid.sync();

    // ---- Phase B2 (blocks 0..63): scalar reduce + inv_denom ---------------
    if (bid < 64) {
        if (tid < 64) red[tid] = bsum[tid];
        __syncthreads();
#pragma unroll
        for (int off = 32; off > 0; off >>= 1) {
            if (tid < off) red[tid] += red[tid + off];
            __syncthreads();
        }
        const float c = (red[0] / (float)D) / 100.0f;
        const int d = bid * 256 + tid;
        inv[d] = 1.0f / (nv[d] + c);
    }
    grid.sync();

    // ---- Phase C: per-row argmax + copy-with-substitution -----------------
    for (int rr = 0; rr < ROWS_PER_BLOCK; ++rr) {
        const int row = bid * ROWS_PER_BLOCK + rr;
        const float* hrow = h + (size_t)row * D;
        float* orow = out + (size_t)row * D;

        float best = -1.0f;
        int bidx = 0;
#pragma unroll
        for (int i = 0; i < 16; ++i) {
            const int c = i * 1024 + tid * 4;
            const float4 v = *reinterpret_cast<const float4*>(hrow + c);
            const float4 m = *reinterpret_cast<const float4*>(nm + c);
            const float4 w = *reinterpret_cast<const float4*>(inv + c);
            *reinterpret_cast<float4*>(orow + c) = v;
            const float dx = v.x - m.x, dy = v.y - m.y, dz = v.z - m.z, dw = v.w - m.w;
            const float sx = dx * dx * w.x;
            const float sy = dy * dy * w.y;
            const float sz = dz * dz * w.z;
            const float sw = dw * dw * w.w;
            if (sx > best) { best = sx; bidx = c + 0; }
            if (sy > best) { best = sy; bidx = c + 1; }
            if (sz > best) { best = sz; bidx = c + 2; }
            if (sw > best) { best = sw; bidx = c + 3; }
        }

        ss[tid] = best;
        si[tid] = bidx;
        __syncthreads();
#pragma unroll
        for (int off = 128; off > 0; off >>= 1) {
            if (tid < off) {
                const float so = ss[tid + off];
                const int   io = si[tid + off];
                if (so > ss[tid] || (so == ss[tid] && io < si[tid])) {
                    ss[tid] = so;
                    si[tid] = io;
                }
            }
            __syncthreads();
        }
        if (tid == 0) {
            const int widx = si[0];
            orow[widx] = nm[widx];
        }
        __syncthreads();  // protect ss/si reuse next row
    }
}

// ---------------- fallback path: round-1 proven 4-kernel pipeline ----------
__global__ __launch_bounds__(256) void k1_colstats(const float* __restrict__ h,
                                                   float* __restrict__ ps,
                                                   float* __restrict__ pq) {
    phaseA(h, ps, pq, blockIdx.x, threadIdx.x);
}

__global__ __launch_bounds__(256) void k2_colfinal(const float* __restrict__ ps,
                                                   const float* __restrict__ pq,
                                                   const float* __restrict__ h_mean,
                                                   const float* __restrict__ h_var,
                                                   float* __restrict__ nm,
                                                   float* __restrict__ nv,
                                                   float* __restrict__ bsum) {
    const int d = blockIdx.x * 256 + threadIdx.x;
    float s = 0.f, q = 0.f;
#pragma unroll
    for (int c = 0; c < NCHUNK; ++c) {
        s += ps[c * D + d];
        q += pq[c * D + d];
    }
    constexpr float invB = 1.0f / (float)B;
    const float hu = s * invB;
    const float hv = q * invB - hu * hu;
    const float hm  = h_mean[d];
    const float hvr = h_var[d];
    const float du  = hu - hm;
    const float newvar  = (hvr * (10.0f - invB) + hv + (du * du) / 1.1f) / (11.0f - invB);
    const float newmean = (hm * 10.0f + hu) / 11.0f;
    nm[d] = newmean;
    nv[d] = newvar;

    __shared__ float red[256];
    red[threadIdx.x] = newvar;
    __syncthreads();
#pragma unroll
    for (int off = 128; off > 0; off >>= 1) {
        if (threadIdx.x < off) red[threadIdx.x] += red[threadIdx.x + off];
        __syncthreads();
    }
    if (threadIdx.x == 0) bsum[blockIdx.x] = red[0];
}

__global__ __launch_bounds__(256) void k2c_invden(const float* __restrict__ nv,
                                                  const float* __restrict__ bsum,
                                                  float* __restrict__ invden) {
    __shared__ float red[64];
    if (threadIdx.x < 64) red[threadIdx.x] = bsum[threadIdx.x];
    __syncthreads();
#pragma unroll
    for (int off = 32; off > 0; off >>= 1) {
        if (threadIdx.x < off) red[threadIdx.x] += red[threadIdx.x + off];
        __syncthreads();
    }
    const float c = (red[0] / (float)D) / 100.0f;
    const int d = blockIdx.x * 256 + threadIdx.x;
    invden[d] = 1.0f / (nv[d] + c);
}

__global__ __launch_bounds__(256) void k3_punish(const float* __restrict__ h,
                                                 const float* __restrict__ nm,
                                                 const float* __restrict__ invden,
                                                 float* __restrict__ out) {
    const int row = blockIdx.x;
    const float* hrow = h + (size_t)row * D;
    float* orow = out + (size_t)row * D;

    float best = -1.0f;
    int bidx = 0;
#pragma unroll
    for (int i = 0; i < 16; ++i) {
        const int c = i * 1024 + threadIdx.x * 4;
        const float4 v = *reinterpret_cast<const float4*>(hrow + c);
        const float4 m = *reinterpret_cast<const float4*>(nm + c);
        const float4 w = *reinterpret_cast<const float4*>(invden + c);
        *reinterpret_cast<float4*>(orow + c) = v;
        const float dx = v.x - m.x, dy = v.y - m.y, dz = v.z - m.z, dw = v.w - m.w;
        const float sx = dx * dx * w.x;
        const float sy = dy * dy * w.y;
        const float sz = dz * dz * w.z;
        const float sw = dw * dw * w.w;
        if (sx > best) { best = sx; bidx = c + 0; }
        if (sy > best) { best = sy; bidx = c + 1; }
        if (sz > best) { best = sz; bidx = c + 2; }
        if (sw > best) { best = sw; bidx = c + 3; }
    }

    __shared__ float ss[256];
    __shared__ int   si[256];
    ss[threadIdx.x] = best;
    si[threadIdx.x] = bidx;
    __syncthreads();
#pragma unroll
    for (int off = 128; off > 0; off >>= 1) {
        if (threadIdx.x < off) {
            const float so = ss[threadIdx.x + off];
            const int   io = si[threadIdx.x + off];
            if (so > ss[threadIdx.x] || (so == ss[threadIdx.x] && io < si[threadIdx.x])) {
                ss[threadIdx.x] = so;
                si[threadIdx.x] = io;
            }
        }
        __syncthreads();
    }
    if (threadIdx.x == 0) {
        const int widx = si[0];
        orow[widx] = nm[widx];
    }
}

}  // namespace

extern "C" void kernel_launch(void* const* d_in, const int* in_sizes, int n_in,
                              void* d_out, int out_size, void* d_ws, size_t ws_size,
                              hipStream_t stream) {
    const float* h      = (const float*)d_in[0];
    const float* h_mean = (const float*)d_in[1];
    const float* h_var  = (const float*)d_in[2];
    float* out = (float*)d_out;

    // ws layout (floats): ps[NCHUNK*D] | pq[NCHUNK*D] | nm[D] | nv[D] | inv[D] | bsum[64]
    float* ws  = (float*)d_ws;
    float* ps   = ws;
    float* pq   = ps + NCHUNK * D;
    float* nm   = pq + NCHUNK * D;
    float* nv   = nm + D;
    float* inv  = nv + D;
    float* bsum = inv + D;

    void* args[] = {(void*)&h, (void*)&h_mean, (void*)&h_var, (void*)&out,
                    (void*)&ps, (void*)&pq, (void*)&nm, (void*)&nv,
                    (void*)&inv, (void*)&bsum};
    hipError_t err = hipLaunchCooperativeKernel(reinterpret_cast<void*>(kfused),
                                                dim3(GRID), dim3(256), args, 0, stream);
    if (err != hipSuccess) {
        // fallback: proven 4-kernel pipeline (round 1, absmax 0.0)
        k1_colstats<<<NCHUNK * COLBLKS, 256, 0, stream>>>(h, ps, pq);
        k2_colfinal<<<D / 256, 256, 0, stream>>>(ps, pq, h_mean, h_var, nm, nv, bsum);
        k2c_invden<<<D / 256, 256, 0, stream>>>(nv, bsum, inv);
        k3_punish<<<B, 256, 0, stream>>>(h, nm, inv, out);
    }
}

// Round 6
// 264.223 us; speedup vs baseline: 1.6872x; 1.6872x over previous
//
#include <hip/hip_runtime.h>

// B=2048, D=16384 fp32. 4-kernel pipeline (round-1 structure, proven absmax 0.0).
// Round-6 change: k1 restructured to one-column-per-thread scalar accumulation
// (2048 blocks x 256 threads = 32 waves/CU vs round-1's 8). Per-column serial
// chain over r=0..63 is BIT-IDENTICAL to round 1 (vector width does not change
// per-column order), so ps/pq/nm/nv/inv and the argmax selection are unchanged.
// k2/k2c/k3 are byte-for-byte the round-1 kernels (do not touch reduction
// trees: mean(new_var) bits feed every score).

namespace {

constexpr int B = 2048;
constexpr int D = 16384;
constexpr int NCHUNK = 32;                 // row chunks for pass 1
constexpr int ROWS_PER_CHUNK = B / NCHUNK; // 64
constexpr int K1_BLOCKS_PER_CHUNK = D / 256;  // 64 blocks of 256 threads cover D cols
constexpr int K1_GRID = NCHUNK * K1_BLOCKS_PER_CHUNK;  // 2048

// ---- Pass 1: partial column sums / sumsq — one column per thread ------------
__global__ __launch_bounds__(256) void k1_colstats(const float* __restrict__ h,
                                                   float* __restrict__ ps,
                                                   float* __restrict__ pq) {
    const int chunk = blockIdx.x >> 6;                    // / K1_BLOCKS_PER_CHUNK
    const int col   = (blockIdx.x & 63) * 256 + threadIdx.x;
    const float* base = h + (size_t)(chunk * ROWS_PER_CHUNK) * D + col;
    float s = 0.f, q = 0.f;
#pragma unroll 16
    for (int r = 0; r < ROWS_PER_CHUNK; ++r) {
        const float v = base[(size_t)r * D];
        s += v;
        q = fmaf(v, v, q);
    }
    ps[chunk * D + col] = s;
    pq[chunk * D + col] = q;
}

// ---- Pass 2: finalize per-column stats, block-partial sum of new_var --------
__global__ __launch_bounds__(256) void k2_colfinal(const float* __restrict__ ps,
                                                   const float* __restrict__ pq,
                                                   const float* __restrict__ h_mean,
                                                   const float* __restrict__ h_var,
                                                   float* __restrict__ nm,
                                                   float* __restrict__ nv,
                                                   float* __restrict__ bsum) {
    const int d = blockIdx.x * 256 + threadIdx.x;
    float s = 0.f, q = 0.f;
#pragma unroll
    for (int c = 0; c < NCHUNK; ++c) {
        s += ps[c * D + d];
        q += pq[c * D + d];
    }
    constexpr float invB = 1.0f / (float)B;
    const float hu = s * invB;
    const float hv = q * invB - hu * hu;   // biased variance
    const float hm  = h_mean[d];
    const float hvr = h_var[d];
    const float du  = hu - hm;
    // new_var = (h_var*(U-1/B) + h_v + (h_u-h_mean)^2/(1+1/U)) / (U+1-1/B), U=10
    const float newvar  = (hvr * (10.0f - invB) + hv + (du * du) / 1.1f) / (11.0f - invB);
    const float newmean = (hm * 10.0f + hu) / 11.0f;
    nm[d] = newmean;
    nv[d] = newvar;

    __shared__ float red[256];
    red[threadIdx.x] = newvar;
    __syncthreads();
#pragma unroll
    for (int off = 128; off > 0; off >>= 1) {
        if (threadIdx.x < off) red[threadIdx.x] += red[threadIdx.x + off];
        __syncthreads();
    }
    if (threadIdx.x == 0) bsum[blockIdx.x] = red[0];
}

// ---- Pass 2c: scalar reduce of bsum (64 entries) + inv_denom ----------------
__global__ __launch_bounds__(256) void k2c_invden(const float* __restrict__ nv,
                                                  const float* __restrict__ bsum,
                                                  float* __restrict__ invden) {
    __shared__ float red[64];
    if (threadIdx.x < 64) red[threadIdx.x] = bsum[threadIdx.x];
    __syncthreads();
#pragma unroll
    for (int off = 32; off > 0; off >>= 1) {
        if (threadIdx.x < off) red[threadIdx.x] += red[threadIdx.x + off];
        __syncthreads();
    }
    const float c = (red[0] / (float)D) / 100.0f;  // mean(new_var)/100
    const int d = blockIdx.x * 256 + threadIdx.x;
    invden[d] = 1.0f / (nv[d] + c);
}

// ---- Pass 3: per-row argmax + copy-with-substitution ------------------------
__global__ __launch_bounds__(256) void k3_punish(const float* __restrict__ h,
                                                 const float* __restrict__ nm,
                                                 const float* __restrict__ invden,
                                                 float* __restrict__ out) {
    const int row = blockIdx.x;
    const float* hrow = h + (size_t)row * D;
    float* orow = out + (size_t)row * D;

    float best = -1.0f;  // scores are >= 0
    int bidx = 0;
#pragma unroll
    for (int i = 0; i < 16; ++i) {
        const int c = i * 1024 + threadIdx.x * 4;
        const float4 v = *reinterpret_cast<const float4*>(hrow + c);
        const float4 m = *reinterpret_cast<const float4*>(nm + c);
        const float4 w = *reinterpret_cast<const float4*>(invden + c);
        *reinterpret_cast<float4*>(orow + c) = v;  // copy-through
        const float dx = v.x - m.x, dy = v.y - m.y, dz = v.z - m.z, dw = v.w - m.w;
        const float sx = dx * dx * w.x;
        const float sy = dy * dy * w.y;
        const float sz = dz * dz * w.z;
        const float sw = dw * dw * w.w;
        // strict > keeps the FIRST max in increasing-d scan order (matches jnp.argmax)
        if (sx > best) { best = sx; bidx = c + 0; }
        if (sy > best) { best = sy; bidx = c + 1; }
        if (sz > best) { best = sz; bidx = c + 2; }
        if (sw > best) { best = sw; bidx = c + 3; }
    }

    __shared__ float ss[256];
    __shared__ int   si[256];
    ss[threadIdx.x] = best;
    si[threadIdx.x] = bidx;
    __syncthreads();
#pragma unroll
    for (int off = 128; off > 0; off >>= 1) {
        if (threadIdx.x < off) {
            const float so = ss[threadIdx.x + off];
            const int   io = si[threadIdx.x + off];
            if (so > ss[threadIdx.x] || (so == ss[threadIdx.x] && io < si[threadIdx.x])) {
                ss[threadIdx.x] = so;
                si[threadIdx.x] = io;
            }
        }
        __syncthreads();
    }
    // barrier above guarantees all copy-through stores in this block are complete
    if (threadIdx.x == 0) {
        const int widx = si[0];
        orow[widx] = nm[widx];
    }
}

}  // namespace

extern "C" void kernel_launch(void* const* d_in, const int* in_sizes, int n_in,
                              void* d_out, int out_size, void* d_ws, size_t ws_size,
                              hipStream_t stream) {
    const float* h      = (const float*)d_in[0];
    const float* h_mean = (const float*)d_in[1];
    const float* h_var  = (const float*)d_in[2];
    float* out = (float*)d_out;

    // ws layout (floats): ps[NCHUNK*D] | pq[NCHUNK*D] | nm[D] | nv[D] | inv[D] | bsum[64]
    float* ws  = (float*)d_ws;
    float* ps  = ws;
    float* pq  = ps + NCHUNK * D;
    float* nm  = pq + NCHUNK * D;
    float* nv  = nm + D;
    float* inv = nv + D;
    float* bsum = inv + D;

    k1_colstats<<<K1_GRID, 256, 0, stream>>>(h, ps, pq);
    k2_colfinal<<<D / 256, 256, 0, stream>>>(ps, pq, h_mean, h_var, nm, nv, bsum);
    k2c_invden<<<D / 256, 256, 0, stream>>>(nv, bsum, inv);
    k3_punish<<<B, 256, 0, stream>>>(h, nm, inv, out);
}